// Round 18
// baseline (174.160 us; speedup 1.0000x reference)
//
#include <hip/hip_runtime.h>
#include <hip/hip_bf16.h>

#define S 2048
#define DM 2048
#define H 16
#define HD 128

using bf16 = __hip_bfloat16;
typedef __attribute__((ext_vector_type(8))) short bf16x8;
typedef __attribute__((ext_vector_type(8))) unsigned short u16x8;
typedef __attribute__((ext_vector_type(4))) float f32x4;

__device__ __forceinline__ unsigned short f2bu(float f) {
  bf16 b = __float2bfloat16(f);
  union { bf16 b; unsigned short u; } cv; cv.b = b; return cv.u;
}
__device__ __forceinline__ float bu2f(unsigned short u) {
  union { bf16 b; unsigned short u; } cv; cv.u = u; return __bfloat162float(cv.b);
}

__device__ __forceinline__ void async_copy16(const void* g, void* l) {
  __builtin_amdgcn_global_load_lds(
      (const __attribute__((address_space(1))) void*)g,
      (__attribute__((address_space(3))) void*)l, 16, 0, 0);
}

// ---------------- 2. weights transpose-convert (z=0..4) + x convert (z=5) ----------------
__global__ __launch_bounds__(256) void wtrans_kernel(
    const float* __restrict__ s0, const float* __restrict__ s1, const float* __restrict__ s2,
    const float* __restrict__ s3, const float* __restrict__ s4,
    unsigned short* __restrict__ d0, unsigned short* __restrict__ d1, unsigned short* __restrict__ d2,
    unsigned short* __restrict__ d3, unsigned short* __restrict__ d4,
    const float* __restrict__ x, unsigned short* __restrict__ xb) {
  __shared__ float tile[64][65];
  int z = blockIdx.z;
  int tid = threadIdx.x;
  int by = blockIdx.y * 64;
  int bx = blockIdx.x * 64;
  int r0 = tid >> 4;
  int c0 = (tid & 15) * 4;
  if (z == 5) {
#pragma unroll
    for (int i = 0; i < 4; i++) {
      int row = by + r0 + i * 16;
      float4 t = *(const float4*)(x + (size_t)row * DM + bx + c0);
      ushort4 o;
      o.x = f2bu(t.x); o.y = f2bu(t.y); o.z = f2bu(t.z); o.w = f2bu(t.w);
      *(ushort4*)(xb + (size_t)row * DM + bx + c0) = o;
    }
    return;
  }
  const float* src = z == 0 ? s0 : z == 1 ? s1 : z == 2 ? s2 : z == 3 ? s3 : s4;
  unsigned short* dst = z == 0 ? d0 : z == 1 ? d1 : z == 2 ? d2 : z == 3 ? d3 : d4;
#pragma unroll
  for (int i = 0; i < 4; i++) {
    int row = r0 + i * 16;
    float4 t = *(const float4*)(src + (size_t)(by + row) * DM + bx + c0);
    tile[row][c0 + 0] = t.x; tile[row][c0 + 1] = t.y;
    tile[row][c0 + 2] = t.z; tile[row][c0 + 3] = t.w;
  }
  __syncthreads();
#pragma unroll
  for (int i = 0; i < 4; i++) {
    int nrow = r0 + i * 16;
    ushort4 o;
    o.x = f2bu(tile[c0 + 0][nrow]);
    o.y = f2bu(tile[c0 + 1][nrow]);
    o.z = f2bu(tile[c0 + 2][nrow]);
    o.w = f2bu(tile[c0 + 3][nrow]);
    *(ushort4*)(dst + (size_t)(bx + nrow) * DM + by + c0) = o;
  }
}

// ---------------- 3. fused QKVG GEMM: 256x256, 8-wave, 8-phase counted-vmcnt ----------------
// Hot loop identical to the measured-best round-13 kernel. Epilogue reworked:
// LDS-bounce to form fully-coalesced 16B global stores (fixes 2.2x write amp).
__device__ __forceinline__ void stage_half(const unsigned short* gbase, char* ldsbase, int tid) {
#pragma unroll
  for (int r = 0; r < 2; r++) {
    int a = r * 8192 + tid * 16;
    int row = a >> 7;
    int cb = (a & 127) ^ ((row & 7) << 4);
    async_copy16((const unsigned char*)(gbase + (size_t)row * DM) + cb, ldsbase + a);
  }
}

#define LDB4(dst, base, kkofs)                                                                     \
  _Pragma("unroll") for (int nt = 0; nt < 4; ++nt) {                                               \
    int lr = blr0 + nt * 16;                                                                       \
    dst[nt] = *(const bf16x8*)((base) + bhalf + lr * 128 + (((kkofs) + quad * 16) ^ ((lr & 7) << 4))); \
  }
#define LDA4(dst, base, kkofs)                                                                     \
  _Pragma("unroll") for (int mt = 0; mt < 4; ++mt) {                                               \
    int lr = mt * 32 + wm * 16 + r16;                                                              \
    dst[mt] = *(const bf16x8*)((base) + lr * 128 + (((kkofs) + quad * 16) ^ ((lr & 7) << 4)));     \
  }
#define MFMA16(accbase, af, bf)                                                                    \
  _Pragma("unroll") for (int mt = 0; mt < 4; ++mt)                                                 \
    _Pragma("unroll") for (int nt = 0; nt < 4; ++nt)                                               \
      acc[accbase + mt][nt] = __builtin_amdgcn_mfma_f32_16x16x32_bf16(af[mt], bf[nt], acc[accbase + mt][nt], 0, 0, 0);
#define PHASE_SYNC()                                            \
  __builtin_amdgcn_s_barrier();                                 \
  asm volatile("s_waitcnt lgkmcnt(0)" ::: "memory");            \
  __builtin_amdgcn_sched_barrier(0);

__global__ __launch_bounds__(512, 2) void gemm_qkvg_kernel(
    const unsigned short* __restrict__ A, const unsigned short* __restrict__ Bm,
    const float* __restrict__ bias0, const float* __restrict__ bias1,
    const float* __restrict__ bias2, const float* __restrict__ bias3,
    unsigned short* __restrict__ C0, unsigned short* __restrict__ C1,
    unsigned short* __restrict__ Vt, unsigned short* __restrict__ C3) {
  __shared__ alignas(16) char smem[131072];
  char* sA = smem;
  char* sB = smem + 65536;
  int tid = threadIdx.x;
  int wg = blockIdx.y * 32 + blockIdx.x;
  int swz = (wg & 7) * 32 + (wg >> 3);
  int bm = (swz >> 5) * 256;
  int bn = (swz & 31) * 256;
  int wid = tid >> 6, lane = tid & 63;
  int wm = wid >> 2, wn = wid & 3;
  int r16 = lane & 15, quad = lane >> 4;
  f32x4 acc[8][4] = {};
  const int bhalf = (wn >> 1) << 14;
  const int blr0 = ((wn & 1) << 6) + r16;

  stage_half(Bm + (size_t)bn * DM, sB, tid);
  stage_half(Bm + (size_t)(bn + 128) * DM, sB + 16384, tid);
  stage_half(A + (size_t)bm * DM, sA, tid);
  stage_half(A + (size_t)(bm + 128) * DM, sA + 16384, tid);
  stage_half(Bm + (size_t)bn * DM + 64, sB + 32768, tid);
  stage_half(Bm + (size_t)(bn + 128) * DM + 64, sB + 49152, tid);
  asm volatile("s_waitcnt vmcnt(6)" ::: "memory");
  __builtin_amdgcn_s_barrier();

  for (int u = 0; u < 16; ++u) {
    const bool more = u < 15;
    const int k1 = (2 * u + 1) * 64;
    const int k2 = (2 * u + 2) * 64;
    const int k3 = (2 * u + 3) * 64;
    bf16x8 a0[4], a1[4], b0[4], b1[4];

    // p1: buf0 {B kk0, A0 kk0}; stage buf1.A0
    LDB4(b0, sB, 0)
    LDA4(a0, sA, 0)
    stage_half(A + (size_t)bm * DM + k1, sA + 32768, tid);
    PHASE_SYNC()
    __builtin_amdgcn_s_setprio(1);
    MFMA16(0, a0, b0)
    __builtin_amdgcn_s_setprio(0);

    // p2: buf0 {B kk1, A0 kk1}; stage buf1.A1; vmcnt(8)
    LDB4(b1, sB, 64)
    LDA4(a1, sA, 64)
    stage_half(A + (size_t)(bm + 128) * DM + k1, sA + 49152, tid);
    asm volatile("s_waitcnt vmcnt(8)" ::: "memory");
    PHASE_SYNC()
    __builtin_amdgcn_s_setprio(1);
    MFMA16(0, a1, b1)
    __builtin_amdgcn_s_setprio(0);

    // p3: buf0 {A1 kk0}; stage buf0.B0
    LDA4(a0, sA + 16384, 0)
    if (more) stage_half(Bm + (size_t)bn * DM + k2, sB, tid);
    PHASE_SYNC()
    __builtin_amdgcn_s_setprio(1);
    MFMA16(4, a0, b0)
    __builtin_amdgcn_s_setprio(0);

    // p4: buf0 {A1 kk1}; stage buf0.B1; vmcnt(6) [final: (2)]
    LDA4(a1, sA + 16384, 64)
    if (more) {
      stage_half(Bm + (size_t)(bn + 128) * DM + k2, sB + 16384, tid);
      asm volatile("s_waitcnt vmcnt(6)" ::: "memory");
    } else {
      asm volatile("s_waitcnt vmcnt(2)" ::: "memory");
    }
    PHASE_SYNC()
    __builtin_amdgcn_s_setprio(1);
    MFMA16(4, a1, b1)
    __builtin_amdgcn_s_setprio(0);

    // p5: buf1 {B kk0, A0 kk0}; stage buf0.A0
    LDB4(b0, sB + 32768, 0)
    LDA4(a0, sA + 32768, 0)
    if (more) stage_half(A + (size_t)bm * DM + k2, sA, tid);
    PHASE_SYNC()
    __builtin_amdgcn_s_setprio(1);
    MFMA16(0, a0, b0)
    __builtin_amdgcn_s_setprio(0);

    // p6: buf1 {B kk1, A0 kk1}; stage buf0.A1; vmcnt(8) [final: (0)]
    LDB4(b1, sB + 32768, 64)
    LDA4(a1, sA + 32768, 64)
    if (more) {
      stage_half(A + (size_t)(bm + 128) * DM + k2, sA + 16384, tid);
      asm volatile("s_waitcnt vmcnt(8)" ::: "memory");
    } else {
      asm volatile("s_waitcnt vmcnt(0)" ::: "memory");
    }
    PHASE_SYNC()
    __builtin_amdgcn_s_setprio(1);
    MFMA16(0, a1, b1)
    __builtin_amdgcn_s_setprio(0);

    // p7: buf1 {A1 kk0}; stage buf1.B0
    LDA4(a0, sA + 32768 + 16384, 0)
    if (more) stage_half(Bm + (size_t)bn * DM + k3, sB + 32768, tid);
    PHASE_SYNC()
    __builtin_amdgcn_s_setprio(1);
    MFMA16(4, a0, b0)
    __builtin_amdgcn_s_setprio(0);

    // p8: buf1 {A1 kk1}; stage buf1.B1; vmcnt(6)
    LDA4(a1, sA + 32768 + 16384, 64)
    if (more) {
      stage_half(Bm + (size_t)(bn + 128) * DM + k3, sB + 49152, tid);
      asm volatile("s_waitcnt vmcnt(6)" ::: "memory");
    }
    PHASE_SYNC()
    __builtin_amdgcn_s_setprio(1);
    MFMA16(4, a1, b1)
    __builtin_amdgcn_s_setprio(0);
  }

  // ---- epilogue: LDS bounce -> coalesced 16B stores ----
  // drain own LDS reads, then all waves may safely overwrite smem
  asm volatile("s_waitcnt lgkmcnt(0)" ::: "memory");
  __builtin_amdgcn_s_barrier();

  int ch = bn >> 11;
  const float* bp = ch == 0 ? bias0 : ch == 1 ? bias1 : ch == 2 ? bias2 : bias3;
  int lcb = bn & 2047;
  unsigned short* sOut = (unsigned short*)smem;  // 256x256 bf16 = 128KB
  if (ch == 2) {
    // stage TRANSPOSED: sOut[feature][m], m-bytes XOR-swizzled by feature for banks
#pragma unroll
    for (int nt = 0; nt < 4; ++nt) {
      int lcl = wn * 64 + nt * 16 + r16;
      float bv = bp[lcb + lcl];
      int fsw = (lcl & 7) << 4;
#pragma unroll
      for (int mt = 0; mt < 8; ++mt) {
        int ml = (mt >> 2) * 128 + (mt & 3) * 32 + wm * 16 + quad * 4;
        ushort4 o;
        o.x = f2bu(acc[mt][nt][0] + bv);
        o.y = f2bu(acc[mt][nt][1] + bv);
        o.z = f2bu(acc[mt][nt][2] + bv);
        o.w = f2bu(acc[mt][nt][3] + bv);
        *(ushort4*)((char*)sOut + lcl * 512 + ((ml * 2) ^ fsw)) = o;
      }
    }
    asm volatile("s_waitcnt lgkmcnt(0)" ::: "memory");
    __builtin_amdgcn_s_barrier();
    int fl = tid >> 1, half = tid & 1;
    int fsw = (fl & 7) << 4;
    unsigned short* dst = Vt + (size_t)(lcb + fl) * DM + bm + half * 128;
#pragma unroll
    for (int j = 0; j < 16; ++j) {
      u16x8 v = *(const u16x8*)((char*)sOut + fl * 512 + ((half * 256 + j * 16) ^ fsw));
      *(u16x8*)(dst + j * 8) = v;
    }
  } else {
    unsigned short* Cp = ch == 0 ? C0 : ch == 1 ? C1 : C3;
    // stage row-major: sOut[m][lc]
#pragma unroll
    for (int nt = 0; nt < 4; ++nt) {
      int lcl = wn * 64 + nt * 16 + r16;
      float bv = bp[lcb + lcl];
#pragma unroll
      for (int mt = 0; mt < 8; ++mt) {
        int ml = (mt >> 2) * 128 + (mt & 3) * 32 + wm * 16 + quad * 4;
#pragma unroll
        for (int rr = 0; rr < 4; ++rr)
          sOut[(ml + rr) * 256 + lcl] = f2bu(acc[mt][nt][rr] + bv);
      }
    }
    asm volatile("s_waitcnt lgkmcnt(0)" ::: "memory");
    __builtin_amdgcn_s_barrier();
    int ml2 = tid >> 1, half = tid & 1;
    const unsigned short* src = sOut + ml2 * 256 + half * 128;
    unsigned short* dst = Cp + (size_t)(bm + ml2) * DM + lcb + half * 128;
#pragma unroll
    for (int j = 0; j < 16; ++j)
      *(u16x8*)(dst + j * 8) = *(const u16x8*)(src + j * 8);
  }
}

// ---------------- 8. output NT GEMM: 128x64 tiles, 512 blocks (2/CU), dbuf ----------------
__device__ __forceinline__ void stage_o(const unsigned short* gA, const unsigned short* gB,
                                        char* dA, char* dB, int tid) {
#pragma unroll
  for (int r = 0; r < 4; r++) {
    int a = r * 4096 + tid * 16;
    int row = a >> 7;
    int cb = (a & 127) ^ ((row & 7) << 4);
    async_copy16((const unsigned char*)(gA + (size_t)row * DM) + cb, dA + a);
  }
#pragma unroll
  for (int r = 0; r < 2; r++) {
    int a = r * 4096 + tid * 16;
    int row = a >> 7;
    int cb = (a & 127) ^ ((row & 7) << 4);
    async_copy16((const unsigned char*)(gB + (size_t)row * DM) + cb, dB + a);
  }
}

__global__ __launch_bounds__(256) void gemm_out_kernel(
    const unsigned short* __restrict__ A, const unsigned short* __restrict__ Bp,
    const float* __restrict__ bias, float* __restrict__ C) {
  __shared__ alignas(16) char sA[2][16384];
  __shared__ alignas(16) char sB[2][8192];
  int tid = threadIdx.x;
  int wg = blockIdx.y * 32 + blockIdx.x;
  int swz = (wg & 7) * 64 + (wg >> 3);
  int bm = (swz >> 5) * 128;
  int bn = (swz & 31) * 64;
  int wid = tid >> 6, lane = tid & 63;
  int wm = wid >> 1, wn = wid & 1;
  int r16 = lane & 15, quad = lane >> 4;
  f32x4 acc[4][2] = {};

  stage_o(A + (size_t)bm * DM, Bp + (size_t)bn * DM, sA[0], sB[0], tid);
  asm volatile("s_waitcnt vmcnt(0)" ::: "memory");
  __builtin_amdgcn_s_barrier();

  for (int t = 0; t < 32; ++t) {
    int cur = t & 1;
    bool more = t < 31;
    int kn = (t + 1) * 64;
    if (more)
      stage_o(A + (size_t)bm * DM + kn, Bp + (size_t)bn * DM + kn, sA[cur ^ 1], sB[cur ^ 1], tid);
#pragma unroll
    for (int kk = 0; kk < 2; kk++) {
      bf16x8 af[4], bfr[2];
#pragma unroll
      for (int mt = 0; mt < 4; mt++) {
        int row = wm * 64 + mt * 16 + r16;
        af[mt] = *(const bf16x8*)(sA[cur] + row * 128 + ((kk * 64 + quad * 16) ^ ((row & 7) << 4)));
      }
#pragma unroll
      for (int nt = 0; nt < 2; nt++) {
        int row = wn * 32 + nt * 16 + r16;
        bfr[nt] = *(const bf16x8*)(sB[cur] + row * 128 + ((kk * 64 + quad * 16) ^ ((row & 7) << 4)));
      }
#pragma unroll
      for (int mt = 0; mt < 4; mt++)
#pragma unroll
        for (int nt = 0; nt < 2; nt++)
          acc[mt][nt] = __builtin_amdgcn_mfma_f32_16x16x32_bf16(af[mt], bfr[nt], acc[mt][nt], 0, 0, 0);
    }
    asm volatile("s_waitcnt vmcnt(0)" ::: "memory");
    __builtin_amdgcn_s_barrier();
  }
#pragma unroll
  for (int nt = 0; nt < 2; nt++) {
    int n = bn + wn * 32 + nt * 16 + r16;
    float bv = bias[n];
#pragma unroll
    for (int mt = 0; mt < 4; mt++) {
      int m0 = bm + wm * 64 + mt * 16 + quad * 4;
#pragma unroll
      for (int r = 0; r < 4; r++)
        C[(size_t)(m0 + r) * DM + n] = acc[mt][nt][r] + bv;
    }
  }
}

// ---------------- 4. RoPE + xPos + decay pre-fold (in-place on q,k bf16) ----------------
__global__ __launch_bounds__(256) void rope_kernel(unsigned short* __restrict__ q,
                                                   unsigned short* __restrict__ k) {
  int idx = blockIdx.x * 256 + threadIdx.x;
  int s = idx >> 10;
  int p = idx & 1023;
  int t = p & 63;
  int head = p >> 6;
  int col = (head << 7) + (t << 1);
  size_t off = (size_t)s * DM + col;
  float ang = (float)s * exp2f((float)(-2 * t) * (13.287712379549449f / 128.0f));
  float sn, cs;
  sincosf(ang, &sn, &cs);
  float sb = ((float)(2 * t) + 51.2f) * (1.0f / 179.2f);
  float power = ((float)s - 1024.0f) * (1.0f / 512.0f);
  float scale = exp2f(power * log2f(sb));
  float l2g = log2f(1.0f - exp2f((float)(-5 - head)));
  float qsc = scale * exp2f((float)s * l2g);
  float ksc = (1.0f / scale) * exp2f(-(float)s * l2g);
  unsigned int qu = *(unsigned int*)(q + off);
  float a = bu2f(qu & 0xffff), b = bu2f(qu >> 16);
  float qa = (a * cs - b * sn) * qsc;
  float qb2 = (b * cs + a * sn) * qsc;
  *(unsigned int*)(q + off) = (unsigned int)f2bu(qa) | ((unsigned int)f2bu(qb2) << 16);
  unsigned int ku = *(unsigned int*)(k + off);
  float c2 = bu2f(ku & 0xffff), d2 = bu2f(ku >> 16);
  float ka = (c2 * cs - d2 * sn) * ksc;
  float kb2 = (d2 * cs + c2 * sn) * ksc;
  *(unsigned int*)(k + off) = (unsigned int)f2bu(ka) | ((unsigned int)f2bu(kb2) << 16);
}

// ---------------- 6. retention + fused GroupNorm/SiLU (LDS-staged K/V dbuf) ----------------
__device__ __forceinline__ void stage_kv(const unsigned short* __restrict__ k,
                                         const unsigned short* __restrict__ vt,
                                         int h, int J0, unsigned char* dK,
                                         unsigned char* dV, int tid) {
#pragma unroll
  for (int r = 0; r < 4; r++) {
    int a = r * 4096 + tid * 16;
    int rowk = a >> 8;
    int cbk = (a & 255) ^ ((rowk & 7) << 4);
    async_copy16((const unsigned char*)(k + (size_t)(J0 + rowk) * DM + h * HD) + cbk, dK + a);
    int rowv = a >> 7;
    int cbv = (a & 127) ^ ((rowv & 7) << 4);
    async_copy16((const unsigned char*)(vt + (size_t)(h * HD + rowv) * DM + J0) + cbv, dV + a);
  }
}

__global__ __launch_bounds__(256) void retention_kernel(
    const unsigned short* __restrict__ q, const unsigned short* __restrict__ k,
    const unsigned short* __restrict__ vt, const unsigned short* __restrict__ g,
    unsigned short* __restrict__ y) {
  __shared__ alignas(16) unsigned char sK[2][16384];
  __shared__ alignas(16) unsigned char sV[2][16384];
  __shared__ alignas(16) unsigned char Plds[8192];
  int bx = blockIdx.x;
  int hi = bx >> 8;
  int h = ((bx >> 5) & 7) | (hi << 3);
  int ib = hi ? (bx & 31) : (31 - (bx & 31));
  int I = ib << 6;
  int tid = threadIdx.x, wid = tid >> 6, lane = tid & 63;
  int r16 = lane & 15, quad = lane >> 4;
  bf16x8 aQ[4];
  size_t qrow = (size_t)(I + wid * 16 + r16);
#pragma unroll
  for (int kk = 0; kk < 4; kk++)
    aQ[kk] = *(const bf16x8*)(q + qrow * DM + h * HD + kk * 32 + quad * 8);
  f32x4 acc[8] = {};
  unsigned char* Pw = Plds + wid * 2048;
  stage_kv(k, vt, h, 0, sK[0], sV[0], tid);
  for (int J0 = 0; J0 <= I; J0 += 64) {
    int cur = (J0 >> 6) & 1;
    bool more = (J0 + 64) <= I;
    if (more) stage_kv(k, vt, h, J0 + 64, sK[cur ^ 1], sV[cur ^ 1], tid);
    if (more) { asm volatile("s_waitcnt vmcnt(8)" ::: "memory"); }
    else      { asm volatile("s_waitcnt vmcnt(0)" ::: "memory"); }
    __builtin_amdgcn_s_barrier();
    const unsigned char* sKc = sK[cur];
    const unsigned char* sVc = sV[cur];
    f32x4 sf[4] = {};
#pragma unroll
    for (int nt = 0; nt < 4; nt++) {
      int row = nt * 16 + r16;
#pragma unroll
      for (int kk = 0; kk < 4; kk++) {
        bf16x8 bK = *(const bf16x8*)(sKc + row * 256 + ((kk * 64 + quad * 16) ^ ((row & 7) << 4)));
        sf[nt] = __builtin_amdgcn_mfma_f32_16x16x32_bf16(aQ[kk], bK, sf[nt], 0, 0, 0);
      }
    }
    bool diag = (J0 == I);
#pragma unroll
    for (int nt = 0; nt < 4; nt++) {
      int j = nt * 16 + r16;
#pragma unroll
      for (int r = 0; r < 4; r++) {
        int ii = wid * 16 + quad * 4 + r;
        float pv = sf[nt][r];
        if (diag && (ii - j) < 0) pv = 0.0f;
        int pr = quad * 4 + r;
        int pcb = (nt * 16 + r16) * 2;
        *(unsigned short*)(Pw + pr * 128 + (pcb ^ ((pr & 7) << 4))) = f2bu(pv);
      }
    }
#pragma unroll
    for (int kk2 = 0; kk2 < 2; kk2++) {
      int cb = kk2 * 64 + quad * 16;
      bf16x8 aP = *(const bf16x8*)(Pw + r16 * 128 + (cb ^ ((r16 & 7) << 4)));
#pragma unroll
      for (int nt2 = 0; nt2 < 8; nt2++) {
        int row = nt2 * 16 + r16;
        bf16x8 bV = *(const bf16x8*)(sVc + row * 128 + ((kk2 * 64 + quad * 16) ^ ((row & 7) << 4)));
        acc[nt2] = __builtin_amdgcn_mfma_f32_16x16x32_bf16(aP, bV, acc[nt2], 0, 0, 0);
      }
    }
    __builtin_amdgcn_s_barrier();
  }
#pragma unroll
  for (int r = 0; r < 4; r++) {
    float sum = 0.0f, sq = 0.0f;
#pragma unroll
    for (int nt2 = 0; nt2 < 8; nt2++) {
      float v = acc[nt2][r];
      sum += v; sq += v * v;
    }
#pragma unroll
    for (int o = 1; o <= 8; o <<= 1) {
      sum += __shfl_xor(sum, o, 64);
      sq += __shfl_xor(sq, o, 64);
    }
    float mean = sum * 0.0078125f;
    float var = sq * 0.0078125f - mean * mean;
    float rstd = rsqrtf(var + 1e-5f);
    int i = I + wid * 16 + quad * 4 + r;
    size_t rowbase = (size_t)i * DM + h * HD;
#pragma unroll
    for (int nt2 = 0; nt2 < 8; nt2++) {
      int col = nt2 * 16 + r16;
      float gv = bu2f(g[rowbase + col]);
      float sg = gv / (1.0f + expf(-gv));
      float yv = sg * (acc[nt2][r] - mean) * rstd;
      y[rowbase + col] = f2bu(yv);
    }
  }
}

extern "C" void kernel_launch(void* const* d_in, const int* in_sizes, int n_in,
                              void* d_out, int out_size, void* d_ws, size_t ws_size,
                              hipStream_t stream) {
  (void)in_sizes; (void)n_in; (void)out_size; (void)ws_size;
  const float* x  = (const float*)d_in[0];
  const float* Wq = (const float*)d_in[1];
  const float* bq = (const float*)d_in[2];
  const float* Wk = (const float*)d_in[3];
  const float* bk = (const float*)d_in[4];
  const float* Wv = (const float*)d_in[5];
  const float* bv = (const float*)d_in[6];
  const float* Wg = (const float*)d_in[7];
  const float* bg = (const float*)d_in[8];
  const float* Wo = (const float*)d_in[9];
  const float* bo = (const float*)d_in[10];

  char* ws = (char*)d_ws;
  const size_t MB = 1ull << 20;
  unsigned short* xb   = (unsigned short*)(ws + 0 * MB);
  unsigned short* wcat = (unsigned short*)(ws + 8 * MB);   // 8192 x 2048 bf16 (q|k|v|g)
  unsigned short* wto  = (unsigned short*)(ws + 40 * MB);
  unsigned short* qb   = (unsigned short*)(ws + 48 * MB);
  unsigned short* kb   = (unsigned short*)(ws + 56 * MB);
  unsigned short* gb   = (unsigned short*)(ws + 72 * MB);
  unsigned short* vt   = (unsigned short*)(ws + 80 * MB);
  unsigned short* yb   = (unsigned short*)(ws + 104 * MB);

  wtrans_kernel<<<dim3(32, 32, 6), 256, 0, stream>>>(
      Wq, Wk, Wv, Wg, Wo,
      wcat, wcat + (size_t)2048 * DM, wcat + (size_t)4096 * DM, wcat + (size_t)6144 * DM, wto,
      x, xb);
  gemm_qkvg_kernel<<<dim3(32, 8), 512, 0, stream>>>(
      xb, wcat, bq, bk, bv, bg, qb, kb, vt, gb);
  rope_kernel<<<8192, 256, 0, stream>>>(qb, kb);
  retention_kernel<<<512, 256, 0, stream>>>(qb, kb, vt, gb, yb);
  gemm_out_kernel<<<dim3(32, 16), 256, 0, stream>>>(yb, wto, bo, (float*)d_out);
}

// Round 19
// 169.554 us; speedup vs baseline: 1.0272x; 1.0272x over previous
//
#include <hip/hip_runtime.h>
#include <hip/hip_bf16.h>

#define S 2048
#define DM 2048
#define H 16
#define HD 128

using bf16 = __hip_bfloat16;
typedef __attribute__((ext_vector_type(8))) short bf16x8;
typedef __attribute__((ext_vector_type(8))) unsigned short u16x8;
typedef __attribute__((ext_vector_type(4))) float f32x4;

__device__ __forceinline__ unsigned short f2bu(float f) {
  bf16 b = __float2bfloat16(f);
  union { bf16 b; unsigned short u; } cv; cv.b = b; return cv.u;
}
__device__ __forceinline__ float bu2f(unsigned short u) {
  union { bf16 b; unsigned short u; } cv; cv.u = u; return __bfloat162float(cv.b);
}

__device__ __forceinline__ void async_copy16(const void* g, void* l) {
  __builtin_amdgcn_global_load_lds(
      (const __attribute__((address_space(1))) void*)g,
      (__attribute__((address_space(3))) void*)l, 16, 0, 0);
}

// ---------------- 2. weights transpose-convert (z=0..4) + x convert (z=5) ----------------
__global__ __launch_bounds__(256) void wtrans_kernel(
    const float* __restrict__ s0, const float* __restrict__ s1, const float* __restrict__ s2,
    const float* __restrict__ s3, const float* __restrict__ s4,
    unsigned short* __restrict__ d0, unsigned short* __restrict__ d1, unsigned short* __restrict__ d2,
    unsigned short* __restrict__ d3, unsigned short* __restrict__ d4,
    const float* __restrict__ x, unsigned short* __restrict__ xb) {
  __shared__ float tile[64][65];
  int z = blockIdx.z;
  int tid = threadIdx.x;
  int by = blockIdx.y * 64;
  int bx = blockIdx.x * 64;
  int r0 = tid >> 4;
  int c0 = (tid & 15) * 4;
  if (z == 5) {
#pragma unroll
    for (int i = 0; i < 4; i++) {
      int row = by + r0 + i * 16;
      float4 t = *(const float4*)(x + (size_t)row * DM + bx + c0);
      ushort4 o;
      o.x = f2bu(t.x); o.y = f2bu(t.y); o.z = f2bu(t.z); o.w = f2bu(t.w);
      *(ushort4*)(xb + (size_t)row * DM + bx + c0) = o;
    }
    return;
  }
  const float* src = z == 0 ? s0 : z == 1 ? s1 : z == 2 ? s2 : z == 3 ? s3 : s4;
  unsigned short* dst = z == 0 ? d0 : z == 1 ? d1 : z == 2 ? d2 : z == 3 ? d3 : d4;
#pragma unroll
  for (int i = 0; i < 4; i++) {
    int row = r0 + i * 16;
    float4 t = *(const float4*)(src + (size_t)(by + row) * DM + bx + c0);
    tile[row][c0 + 0] = t.x; tile[row][c0 + 1] = t.y;
    tile[row][c0 + 2] = t.z; tile[row][c0 + 3] = t.w;
  }
  __syncthreads();
#pragma unroll
  for (int i = 0; i < 4; i++) {
    int nrow = r0 + i * 16;
    ushort4 o;
    o.x = f2bu(tile[c0 + 0][nrow]);
    o.y = f2bu(tile[c0 + 1][nrow]);
    o.z = f2bu(tile[c0 + 2][nrow]);
    o.w = f2bu(tile[c0 + 3][nrow]);
    *(ushort4*)(dst + (size_t)(bx + nrow) * DM + by + c0) = o;
  }
}

// ---------------- 3. fused QKVG GEMM: 256x256, 8-wave, 8-phase counted-vmcnt ----------------
__device__ __forceinline__ void stage_half(const unsigned short* gbase, char* ldsbase, int tid) {
#pragma unroll
  for (int r = 0; r < 2; r++) {
    int a = r * 8192 + tid * 16;
    int row = a >> 7;
    int cb = (a & 127) ^ ((row & 7) << 4);
    async_copy16((const unsigned char*)(gbase + (size_t)row * DM) + cb, ldsbase + a);
  }
}

#define LDB4(dst, base, kkofs)                                                                     \
  _Pragma("unroll") for (int nt = 0; nt < 4; ++nt) {                                               \
    int lr = blr0 + nt * 16;                                                                       \
    dst[nt] = *(const bf16x8*)((base) + bhalf + lr * 128 + (((kkofs) + quad * 16) ^ ((lr & 7) << 4))); \
  }
#define LDA4(dst, base, kkofs)                                                                     \
  _Pragma("unroll") for (int mt = 0; mt < 4; ++mt) {                                               \
    int lr = mt * 32 + wm * 16 + r16;                                                              \
    dst[mt] = *(const bf16x8*)((base) + lr * 128 + (((kkofs) + quad * 16) ^ ((lr & 7) << 4)));     \
  }
#define MFMA16(accbase, af, bf)                                                                    \
  _Pragma("unroll") for (int mt = 0; mt < 4; ++mt)                                                 \
    _Pragma("unroll") for (int nt = 0; nt < 4; ++nt)                                               \
      acc[accbase + mt][nt] = __builtin_amdgcn_mfma_f32_16x16x32_bf16(af[mt], bf[nt], acc[accbase + mt][nt], 0, 0, 0);
#define PHASE_SYNC()                                            \
  __builtin_amdgcn_s_barrier();                                 \
  asm volatile("s_waitcnt lgkmcnt(0)" ::: "memory");            \
  __builtin_amdgcn_sched_barrier(0);

__global__ __launch_bounds__(512, 2) void gemm_qkvg_kernel(
    const unsigned short* __restrict__ A, const unsigned short* __restrict__ Bm,
    const float* __restrict__ bias0, const float* __restrict__ bias1,
    const float* __restrict__ bias2, const float* __restrict__ bias3,
    unsigned short* __restrict__ C0, unsigned short* __restrict__ C1,
    unsigned short* __restrict__ Vt, unsigned short* __restrict__ C3) {
  __shared__ alignas(16) char smem[131072];
  char* sA = smem;
  char* sB = smem + 65536;
  int tid = threadIdx.x;
  int wg = blockIdx.y * 32 + blockIdx.x;
  int swz = (wg & 7) * 32 + (wg >> 3);
  int bm = (swz >> 5) * 256;
  int bn = (swz & 31) * 256;
  int wid = tid >> 6, lane = tid & 63;
  int wm = wid >> 2, wn = wid & 3;
  int r16 = lane & 15, quad = lane >> 4;
  f32x4 acc[8][4] = {};
  const int bhalf = (wn >> 1) << 14;
  const int blr0 = ((wn & 1) << 6) + r16;

  stage_half(Bm + (size_t)bn * DM, sB, tid);
  stage_half(Bm + (size_t)(bn + 128) * DM, sB + 16384, tid);
  stage_half(A + (size_t)bm * DM, sA, tid);
  stage_half(A + (size_t)(bm + 128) * DM, sA + 16384, tid);
  stage_half(Bm + (size_t)bn * DM + 64, sB + 32768, tid);
  stage_half(Bm + (size_t)(bn + 128) * DM + 64, sB + 49152, tid);
  asm volatile("s_waitcnt vmcnt(6)" ::: "memory");
  __builtin_amdgcn_s_barrier();

  for (int u = 0; u < 16; ++u) {
    const bool more = u < 15;
    const int k1 = (2 * u + 1) * 64;
    const int k2 = (2 * u + 2) * 64;
    const int k3 = (2 * u + 3) * 64;
    bf16x8 a0[4], a1[4], b0[4], b1[4];

    // p1: buf0 {B kk0, A0 kk0}; stage buf1.A0
    LDB4(b0, sB, 0)
    LDA4(a0, sA, 0)
    stage_half(A + (size_t)bm * DM + k1, sA + 32768, tid);
    PHASE_SYNC()
    __builtin_amdgcn_s_setprio(1);
    MFMA16(0, a0, b0)
    __builtin_amdgcn_s_setprio(0);

    // p2: buf0 {B kk1, A0 kk1}; stage buf1.A1; vmcnt(8)
    LDB4(b1, sB, 64)
    LDA4(a1, sA, 64)
    stage_half(A + (size_t)(bm + 128) * DM + k1, sA + 49152, tid);
    asm volatile("s_waitcnt vmcnt(8)" ::: "memory");
    PHASE_SYNC()
    __builtin_amdgcn_s_setprio(1);
    MFMA16(0, a1, b1)
    __builtin_amdgcn_s_setprio(0);

    // p3: buf0 {A1 kk0}; stage buf0.B0
    LDA4(a0, sA + 16384, 0)
    if (more) stage_half(Bm + (size_t)bn * DM + k2, sB, tid);
    PHASE_SYNC()
    __builtin_amdgcn_s_setprio(1);
    MFMA16(4, a0, b0)
    __builtin_amdgcn_s_setprio(0);

    // p4: buf0 {A1 kk1}; stage buf0.B1; vmcnt(6) [final: (2)]
    LDA4(a1, sA + 16384, 64)
    if (more) {
      stage_half(Bm + (size_t)(bn + 128) * DM + k2, sB + 16384, tid);
      asm volatile("s_waitcnt vmcnt(6)" ::: "memory");
    } else {
      asm volatile("s_waitcnt vmcnt(2)" ::: "memory");
    }
    PHASE_SYNC()
    __builtin_amdgcn_s_setprio(1);
    MFMA16(4, a1, b1)
    __builtin_amdgcn_s_setprio(0);

    // p5: buf1 {B kk0, A0 kk0}; stage buf0.A0
    LDB4(b0, sB + 32768, 0)
    LDA4(a0, sA + 32768, 0)
    if (more) stage_half(A + (size_t)bm * DM + k2, sA, tid);
    PHASE_SYNC()
    __builtin_amdgcn_s_setprio(1);
    MFMA16(0, a0, b0)
    __builtin_amdgcn_s_setprio(0);

    // p6: buf1 {B kk1, A0 kk1}; stage buf0.A1; vmcnt(8) [final: (0)]
    LDB4(b1, sB + 32768, 64)
    LDA4(a1, sA + 32768, 64)
    if (more) {
      stage_half(A + (size_t)(bm + 128) * DM + k2, sA + 16384, tid);
      asm volatile("s_waitcnt vmcnt(8)" ::: "memory");
    } else {
      asm volatile("s_waitcnt vmcnt(0)" ::: "memory");
    }
    PHASE_SYNC()
    __builtin_amdgcn_s_setprio(1);
    MFMA16(0, a1, b1)
    __builtin_amdgcn_s_setprio(0);

    // p7: buf1 {A1 kk0}; stage buf1.B0
    LDA4(a0, sA + 32768 + 16384, 0)
    if (more) stage_half(Bm + (size_t)bn * DM + k3, sB + 32768, tid);
    PHASE_SYNC()
    __builtin_amdgcn_s_setprio(1);
    MFMA16(4, a0, b0)
    __builtin_amdgcn_s_setprio(0);

    // p8: buf1 {A1 kk1}; stage buf1.B1; vmcnt(6)
    LDA4(a1, sA + 32768 + 16384, 64)
    if (more) {
      stage_half(Bm + (size_t)(bn + 128) * DM + k3, sB + 49152, tid);
      asm volatile("s_waitcnt vmcnt(6)" ::: "memory");
    }
    PHASE_SYNC()
    __builtin_amdgcn_s_setprio(1);
    MFMA16(4, a1, b1)
    __builtin_amdgcn_s_setprio(0);
  }

  // epilogue: bn is 256-aligned -> single 2048-wide chunk per block
  int ch = bn >> 11;
  const float* bp = ch == 0 ? bias0 : ch == 1 ? bias1 : ch == 2 ? bias2 : bias3;
  int lcb = bn & 2047;
  if (ch == 2) {
#pragma unroll
    for (int nt = 0; nt < 4; ++nt) {
      int lc = lcb + wn * 64 + nt * 16 + r16;
      float bv = bp[lc];
#pragma unroll
      for (int mt = 0; mt < 8; ++mt) {
        int m0 = bm + (mt >> 2) * 128 + (mt & 3) * 32 + wm * 16 + quad * 4;
        ushort4 o;
        o.x = f2bu(acc[mt][nt][0] + bv);
        o.y = f2bu(acc[mt][nt][1] + bv);
        o.z = f2bu(acc[mt][nt][2] + bv);
        o.w = f2bu(acc[mt][nt][3] + bv);
        *(ushort4*)(Vt + (size_t)lc * DM + m0) = o;
      }
    }
  } else {
    unsigned short* Cp = ch == 0 ? C0 : ch == 1 ? C1 : C3;
#pragma unroll
    for (int nt = 0; nt < 4; ++nt) {
      int lc = lcb + wn * 64 + nt * 16 + r16;
      float bv = bp[lc];
#pragma unroll
      for (int mt = 0; mt < 8; ++mt) {
        int m0 = bm + (mt >> 2) * 128 + (mt & 3) * 32 + wm * 16 + quad * 4;
#pragma unroll
        for (int rr = 0; rr < 4; ++rr)
          Cp[(size_t)(m0 + rr) * DM + lc] = f2bu(acc[mt][nt][rr] + bv);
      }
    }
  }
}

// ---------------- 8. output NT GEMM: 128x64 tiles, 512 blocks (2/CU), dbuf ----------------
__device__ __forceinline__ void stage_o(const unsigned short* gA, const unsigned short* gB,
                                        char* dA, char* dB, int tid) {
#pragma unroll
  for (int r = 0; r < 4; r++) {
    int a = r * 4096 + tid * 16;
    int row = a >> 7;
    int cb = (a & 127) ^ ((row & 7) << 4);
    async_copy16((const unsigned char*)(gA + (size_t)row * DM) + cb, dA + a);
  }
#pragma unroll
  for (int r = 0; r < 2; r++) {
    int a = r * 4096 + tid * 16;
    int row = a >> 7;
    int cb = (a & 127) ^ ((row & 7) << 4);
    async_copy16((const unsigned char*)(gB + (size_t)row * DM) + cb, dB + a);
  }
}

__global__ __launch_bounds__(256) void gemm_out_kernel(
    const unsigned short* __restrict__ A, const unsigned short* __restrict__ Bp,
    const float* __restrict__ bias, float* __restrict__ C) {
  __shared__ alignas(16) char sA[2][16384];
  __shared__ alignas(16) char sB[2][8192];
  int tid = threadIdx.x;
  int wg = blockIdx.y * 32 + blockIdx.x;
  int swz = (wg & 7) * 64 + (wg >> 3);
  int bm = (swz >> 5) * 128;
  int bn = (swz & 31) * 64;
  int wid = tid >> 6, lane = tid & 63;
  int wm = wid >> 1, wn = wid & 1;
  int r16 = lane & 15, quad = lane >> 4;
  f32x4 acc[4][2] = {};

  stage_o(A + (size_t)bm * DM, Bp + (size_t)bn * DM, sA[0], sB[0], tid);
  asm volatile("s_waitcnt vmcnt(0)" ::: "memory");
  __builtin_amdgcn_s_barrier();

  for (int t = 0; t < 32; ++t) {
    int cur = t & 1;
    bool more = t < 31;
    int kn = (t + 1) * 64;
    if (more)
      stage_o(A + (size_t)bm * DM + kn, Bp + (size_t)bn * DM + kn, sA[cur ^ 1], sB[cur ^ 1], tid);
#pragma unroll
    for (int kk = 0; kk < 2; kk++) {
      bf16x8 af[4], bfr[2];
#pragma unroll
      for (int mt = 0; mt < 4; mt++) {
        int row = wm * 64 + mt * 16 + r16;
        af[mt] = *(const bf16x8*)(sA[cur] + row * 128 + ((kk * 64 + quad * 16) ^ ((row & 7) << 4)));
      }
#pragma unroll
      for (int nt = 0; nt < 2; nt++) {
        int row = wn * 32 + nt * 16 + r16;
        bfr[nt] = *(const bf16x8*)(sB[cur] + row * 128 + ((kk * 64 + quad * 16) ^ ((row & 7) << 4)));
      }
#pragma unroll
      for (int mt = 0; mt < 4; mt++)
#pragma unroll
        for (int nt = 0; nt < 2; nt++)
          acc[mt][nt] = __builtin_amdgcn_mfma_f32_16x16x32_bf16(af[mt], bfr[nt], acc[mt][nt], 0, 0, 0);
    }
    asm volatile("s_waitcnt vmcnt(0)" ::: "memory");
    __builtin_amdgcn_s_barrier();
  }
#pragma unroll
  for (int nt = 0; nt < 2; nt++) {
    int n = bn + wn * 32 + nt * 16 + r16;
    float bv = bias[n];
#pragma unroll
    for (int mt = 0; mt < 4; mt++) {
      int m0 = bm + wm * 64 + mt * 16 + quad * 4;
#pragma unroll
      for (int r = 0; r < 4; r++)
        C[(size_t)(m0 + r) * DM + n] = acc[mt][nt][r] + bv;
    }
  }
}

// ---------------- 4. RoPE + xPos + decay pre-fold (in-place on q,k bf16) ----------------
__global__ __launch_bounds__(256) void rope_kernel(unsigned short* __restrict__ q,
                                                   unsigned short* __restrict__ k) {
  int idx = blockIdx.x * 256 + threadIdx.x;
  int s = idx >> 10;
  int p = idx & 1023;
  int t = p & 63;
  int head = p >> 6;
  int col = (head << 7) + (t << 1);
  size_t off = (size_t)s * DM + col;
  float ang = (float)s * exp2f((float)(-2 * t) * (13.287712379549449f / 128.0f));
  float sn, cs;
  sincosf(ang, &sn, &cs);
  float sb = ((float)(2 * t) + 51.2f) * (1.0f / 179.2f);
  float power = ((float)s - 1024.0f) * (1.0f / 512.0f);
  float scale = exp2f(power * log2f(sb));
  float l2g = log2f(1.0f - exp2f((float)(-5 - head)));
  float qsc = scale * exp2f((float)s * l2g);
  float ksc = (1.0f / scale) * exp2f(-(float)s * l2g);
  unsigned int qu = *(unsigned int*)(q + off);
  float a = bu2f(qu & 0xffff), b = bu2f(qu >> 16);
  float qa = (a * cs - b * sn) * qsc;
  float qb2 = (b * cs + a * sn) * qsc;
  *(unsigned int*)(q + off) = (unsigned int)f2bu(qa) | ((unsigned int)f2bu(qb2) << 16);
  unsigned int ku = *(unsigned int*)(k + off);
  float c2 = bu2f(ku & 0xffff), d2 = bu2f(ku >> 16);
  float ka = (c2 * cs - d2 * sn) * ksc;
  float kb2 = (d2 * cs + c2 * sn) * ksc;
  *(unsigned int*)(k + off) = (unsigned int)f2bu(ka) | ((unsigned int)f2bu(kb2) << 16);
}

// ---------------- 6. retention + fused GroupNorm/SiLU (LDS-staged K/V dbuf) ----------------
__device__ __forceinline__ void stage_kv(const unsigned short* __restrict__ k,
                                         const unsigned short* __restrict__ vt,
                                         int h, int J0, unsigned char* dK,
                                         unsigned char* dV, int tid) {
#pragma unroll
  for (int r = 0; r < 4; r++) {
    int a = r * 4096 + tid * 16;
    int rowk = a >> 8;
    int cbk = (a & 255) ^ ((rowk & 7) << 4);
    async_copy16((const unsigned char*)(k + (size_t)(J0 + rowk) * DM + h * HD) + cbk, dK + a);
    int rowv = a >> 7;
    int cbv = (a & 127) ^ ((rowv & 7) << 4);
    async_copy16((const unsigned char*)(vt + (size_t)(h * HD + rowv) * DM + J0) + cbv, dV + a);
  }
}

__global__ __launch_bounds__(256) void retention_kernel(
    const unsigned short* __restrict__ q, const unsigned short* __restrict__ k,
    const unsigned short* __restrict__ vt, const unsigned short* __restrict__ g,
    unsigned short* __restrict__ y) {
  __shared__ alignas(16) unsigned char sK[2][16384];
  __shared__ alignas(16) unsigned char sV[2][16384];
  __shared__ alignas(16) unsigned char Plds[8192];
  int bx = blockIdx.x;
  int hi = bx >> 8;
  int h = ((bx >> 5) & 7) | (hi << 3);
  int ib = hi ? (bx & 31) : (31 - (bx & 31));
  int I = ib << 6;
  int tid = threadIdx.x, wid = tid >> 6, lane = tid & 63;
  int r16 = lane & 15, quad = lane >> 4;
  bf16x8 aQ[4];
  size_t qrow = (size_t)(I + wid * 16 + r16);
#pragma unroll
  for (int kk = 0; kk < 4; kk++)
    aQ[kk] = *(const bf16x8*)(q + qrow * DM + h * HD + kk * 32 + quad * 8);
  f32x4 acc[8] = {};
  unsigned char* Pw = Plds + wid * 2048;
  stage_kv(k, vt, h, 0, sK[0], sV[0], tid);
  for (int J0 = 0; J0 <= I; J0 += 64) {
    int cur = (J0 >> 6) & 1;
    bool more = (J0 + 64) <= I;
    if (more) stage_kv(k, vt, h, J0 + 64, sK[cur ^ 1], sV[cur ^ 1], tid);
    if (more) { asm volatile("s_waitcnt vmcnt(8)" ::: "memory"); }
    else      { asm volatile("s_waitcnt vmcnt(0)" ::: "memory"); }
    __builtin_amdgcn_s_barrier();
    const unsigned char* sKc = sK[cur];
    const unsigned char* sVc = sV[cur];
    f32x4 sf[4] = {};
#pragma unroll
    for (int nt = 0; nt < 4; nt++) {
      int row = nt * 16 + r16;
#pragma unroll
      for (int kk = 0; kk < 4; kk++) {
        bf16x8 bK = *(const bf16x8*)(sKc + row * 256 + ((kk * 64 + quad * 16) ^ ((row & 7) << 4)));
        sf[nt] = __builtin_amdgcn_mfma_f32_16x16x32_bf16(aQ[kk], bK, sf[nt], 0, 0, 0);
      }
    }
    bool diag = (J0 == I);
#pragma unroll
    for (int nt = 0; nt < 4; nt++) {
      int j = nt * 16 + r16;
#pragma unroll
      for (int r = 0; r < 4; r++) {
        int ii = wid * 16 + quad * 4 + r;
        float pv = sf[nt][r];
        if (diag && (ii - j) < 0) pv = 0.0f;
        int pr = quad * 4 + r;
        int pcb = (nt * 16 + r16) * 2;
        *(unsigned short*)(Pw + pr * 128 + (pcb ^ ((pr & 7) << 4))) = f2bu(pv);
      }
    }
#pragma unroll
    for (int kk2 = 0; kk2 < 2; kk2++) {
      int cb = kk2 * 64 + quad * 16;
      bf16x8 aP = *(const bf16x8*)(Pw + r16 * 128 + (cb ^ ((r16 & 7) << 4)));
#pragma unroll
      for (int nt2 = 0; nt2 < 8; nt2++) {
        int row = nt2 * 16 + r16;
        bf16x8 bV = *(const bf16x8*)(sVc + row * 128 + ((kk2 * 64 + quad * 16) ^ ((row & 7) << 4)));
        acc[nt2] = __builtin_amdgcn_mfma_f32_16x16x32_bf16(aP, bV, acc[nt2], 0, 0, 0);
      }
    }
    __builtin_amdgcn_s_barrier();
  }
#pragma unroll
  for (int r = 0; r < 4; r++) {
    float sum = 0.0f, sq = 0.0f;
#pragma unroll
    for (int nt2 = 0; nt2 < 8; nt2++) {
      float v = acc[nt2][r];
      sum += v; sq += v * v;
    }
#pragma unroll
    for (int o = 1; o <= 8; o <<= 1) {
      sum += __shfl_xor(sum, o, 64);
      sq += __shfl_xor(sq, o, 64);
    }
    float mean = sum * 0.0078125f;
    float var = sq * 0.0078125f - mean * mean;
    float rstd = rsqrtf(var + 1e-5f);
    int i = I + wid * 16 + quad * 4 + r;
    size_t rowbase = (size_t)i * DM + h * HD;
#pragma unroll
    for (int nt2 = 0; nt2 < 8; nt2++) {
      int col = nt2 * 16 + r16;
      float gv = bu2f(g[rowbase + col]);
      float sg = gv / (1.0f + expf(-gv));
      float yv = sg * (acc[nt2][r] - mean) * rstd;
      y[rowbase + col] = f2bu(yv);
    }
  }
}

extern "C" void kernel_launch(void* const* d_in, const int* in_sizes, int n_in,
                              void* d_out, int out_size, void* d_ws, size_t ws_size,
                              hipStream_t stream) {
  (void)in_sizes; (void)n_in; (void)out_size; (void)ws_size;
  const float* x  = (const float*)d_in[0];
  const float* Wq = (const float*)d_in[1];
  const float* bq = (const float*)d_in[2];
  const float* Wk = (const float*)d_in[3];
  const float* bk = (const float*)d_in[4];
  const float* Wv = (const float*)d_in[5];
  const float* bv = (const float*)d_in[6];
  const float* Wg = (const float*)d_in[7];
  const float* bg = (const float*)d_in[8];
  const float* Wo = (const float*)d_in[9];
  const float* bo = (const float*)d_in[10];

  char* ws = (char*)d_ws;
  const size_t MB = 1ull << 20;
  unsigned short* xb   = (unsigned short*)(ws + 0 * MB);
  unsigned short* wcat = (unsigned short*)(ws + 8 * MB);   // 8192 x 2048 bf16 (q|k|v|g)
  unsigned short* wto  = (unsigned short*)(ws + 40 * MB);
  unsigned short* qb   = (unsigned short*)(ws + 48 * MB);
  unsigned short* kb   = (unsigned short*)(ws + 56 * MB);
  unsigned short* gb   = (unsigned short*)(ws + 72 * MB);
  unsigned short* vt   = (unsigned short*)(ws + 80 * MB);
  unsigned short* yb   = (unsigned short*)(ws + 104 * MB);

  wtrans_kernel<<<dim3(32, 32, 6), 256, 0, stream>>>(
      Wq, Wk, Wv, Wg, Wo,
      wcat, wcat + (size_t)2048 * DM, wcat + (size_t)4096 * DM, wcat + (size_t)6144 * DM, wto,
      x, xb);
  gemm_qkvg_kernel<<<dim3(32, 8), 512, 0, stream>>>(
      xb, wcat, bq, bk, bv, bg, qb, kb, vt, gb);
  rope_kernel<<<8192, 256, 0, stream>>>(qb, kb);
  retention_kernel<<<512, 256, 0, stream>>>(qb, kb, vt, gb, yb);
  gemm_out_kernel<<<dim3(32, 16), 256, 0, stream>>>(yb, wto, bo, (float*)d_out);
}